// Round 1
// baseline (815.747 us; speedup 1.0000x reference)
//
#include <hip/hip_runtime.h>

#define NEGV  (-1e9f)
#define EPSF  (1e-7f)

constexpr int Tc  = 1000;
constexpr int Vc  = 1024;
constexpr int Lc  = 100;
constexpr int Sc  = 2 * Lc + 1;   // 201
constexpr int BLK = 256;
constexpr int PF  = 8;            // emission prefetch depth

__device__ __forceinline__ float logadd3(float a, float b, float c) {
    float m = fmaxf(fmaxf(a, b), c);
    return m + __logf(__expf(a - m) + __expf(b - m) + __expf(c - m));
}

__global__ __launch_bounds__(BLK) void ctc_dp_kernel(
    const float* __restrict__ pred,     // [B,T,V] probabilities
    const int*   __restrict__ ilen,     // [B,1]
    const int*   __restrict__ labels,   // [B,L]
    const int*   __restrict__ llen,     // [B,1]
    float*       __restrict__ loss)     // [B] per-utterance loss (workspace)
{
    const int b = blockIdx.x;
    const int s = threadIdx.x;

    const int il = ilen[b];
    const int ll = llen[b];
    const int Tb = min(Tc, il);        // steps 1..Tb-1 update; t>=il frozen

    // Extended label: even s -> blank (V-1), odd s -> labels[s>>1]
    int  col;
    bool allow = false;                // allow_skip (only meaningful with s>=2)
    if (s < Sc) {
        if (s & 1) {
            int idx = s >> 1;
            col = labels[b * Lc + idx];
            allow = (s < 3) || (col != labels[b * Lc + idx - 1]);
        } else {
            col = Vc - 1;
        }
    } else {
        col = Vc - 1;                  // padding threads: harmless valid address
    }
    const bool validf = (s < 2 * ll + 1);

    // alpha double buffer with 2-slot NEG pad at the front so s-1, s-2 reads
    // at s=0,1 fall into NEG without branches.
    __shared__ float buf0[BLK + 2];
    __shared__ float buf1[BLK + 2];
    float* cur = buf0 + 2;
    float* nxt = buf1 + 2;
    if (s < 2) { buf0[s] = NEGV; buf1[s] = NEGV; }

    const float* pbase = pred + ((size_t)b * Tc) * Vc + col;

    // t = 0 init
    float e0 = __logf(pbase[0] + EPSF);
    cur[s] = (s < 2 && validf) ? e0 : NEGV;

    // Prime the emission prefetch pipe (raw probabilities; log applied at use)
    float v[PF];
#pragma unroll
    for (int k = 0; k < PF; ++k) {
        int t = 1 + k;
        v[k] = (t < Tb) ? pbase[(size_t)t * Vc] : 1.0f;
    }
    __syncthreads();

    int t = 1;
    while (t < Tb) {
#pragma unroll
        for (int k = 0; k < PF; ++k) {     // compile-time k -> v[] stays in regs
            if (t < Tb) {                  // block-uniform condition (barrier-safe)
                float emit = __logf(v[k] + EPSF);
                int tn = t + PF;
                v[k] = (tn < Tb) ? pbase[(size_t)tn * Vc] : 1.0f;  // refill pipe

                float a  = cur[s];
                float bb = cur[s - 1];
                float cc = allow ? cur[s - 2] : NEGV;
                float nv = validf ? (logadd3(a, bb, cc) + emit) : NEGV;
                nxt[s] = nv;
                __syncthreads();
                float* tmp = cur; cur = nxt; nxt = tmp;
            }
            ++t;
        }
    }

    if (s == 0) {
        float alab = cur[2 * ll - 1];
        float ablk = cur[2 * ll];
        float m  = fmaxf(alab, ablk);
        float lk = m + __logf(__expf(alab - m) + __expf(ablk - m));
        loss[b] = -lk;
    }
}

__global__ void ctc_reduce_kernel(const float* __restrict__ loss,
                                  float* __restrict__ out, int B)
{
    int lane = threadIdx.x;                 // one wave (64 lanes)
    float x = (lane < B) ? loss[lane] : 0.0f;
#pragma unroll
    for (int off = 32; off > 0; off >>= 1)
        x += __shfl_down(x, off);
    if (lane == 0) out[0] = x / (float)B;
}

extern "C" void kernel_launch(void* const* d_in, const int* in_sizes, int n_in,
                              void* d_out, int out_size, void* d_ws, size_t ws_size,
                              hipStream_t stream)
{
    const float* pred   = (const float*)d_in[0];   // [B,T,V]
    const int*   ilen   = (const int*)d_in[1];     // [B,1]
    const int*   labels = (const int*)d_in[2];     // [B,L]
    const int*   llen   = (const int*)d_in[3];     // [B,1]
    float*       out    = (float*)d_out;           // scalar mean loss
    float*       wsloss = (float*)d_ws;            // [B] scratch

    const int B = in_sizes[1];                     // input_lengths has B elements

    ctc_dp_kernel<<<B, BLK, 0, stream>>>(pred, ilen, labels, llen, wsloss);
    ctc_reduce_kernel<<<1, 64, 0, stream>>>(wsloss, out, B);
}

// Round 3
// 473.727 us; speedup vs baseline: 1.7220x; 1.7220x over previous
//
#include <hip/hip_runtime.h>

#define NEGV  (-1e9f)
#define EPSF  (1e-7f)

constexpr int Tc  = 1000;
constexpr int Vc  = 1024;
constexpr int Lc  = 100;
constexpr int PF  = 8;            // emission prefetch depth (per-column)

// One block = one wave = one batch element. Lane l owns the 4 extended-label
// DP lanes s = 4l..4l+3 in registers; cross-lane s-1/s-2 neighbors come from
// 2 shuffles. No __syncthreads in the T loop -> the compiler emits counted
// vmcnt waits and the PF-deep emission prefetch stays in flight (the R1
// 4-wave+barrier version drained vmcnt(0) every step: ~2170 cy/step).
__global__ __launch_bounds__(64) void ctc_dp_kernel(
    const float* __restrict__ pred,     // [B,T,V] probabilities
    const int*   __restrict__ ilen,     // [B,1]
    const int*   __restrict__ labels,   // [B,L]
    const int*   __restrict__ llen,     // [B,1]
    float*       __restrict__ loss)     // [B] per-utterance loss
{
    const int b = blockIdx.x;
    const int l = threadIdx.x;          // 0..63

    const int il = ilen[b];
    const int ll = llen[b];
    const int Tb = min(Tc, il);         // reference freezes alpha at t >= il

    // Extended labels: s=4l (blank), 4l+1 (lab0), 4l+2 (blank), 4l+3 (lab1)
    const int* lab = labels + b * Lc;
    const int lab0 = lab[min(2 * l,     Lc - 1)];   // clamped: padding lanes in-bounds
    const int lab1 = lab[min(2 * l + 1, Lc - 1)];
    const int labm = lab[max(2 * l - 1, 0)];
    const bool allow1 = (l == 0) || (lab0 != labm); // skip allowed at s=4l+1
    const bool allow3 = (lab1 != lab0);             // skip allowed at s=4l+3

    const int Sv = 2 * ll + 1;
    const bool valid0 = (4 * l + 0) < Sv;
    const bool valid1 = (4 * l + 1) < Sv;
    const bool valid2 = (4 * l + 2) < Sv;
    const bool valid3 = (4 * l + 3) < Sv;

    const float* pb     = pred + (size_t)b * Tc * Vc;
    const float* base_b = pb + (Vc - 1);            // blank column (wave-uniform)
    const float* base_0 = pb + lab0;
    const float* base_1 = pb + lab1;

    // t = 0 init (ln domain)
    float a0 = NEGV, a1 = NEGV, a2 = NEGV, a3 = NEGV;
    if (l == 0) {
        a0 = __logf(base_b[0] + EPSF);              // s=0: blank
        a1 = __logf(base_0[0] + EPSF);              // s=1: first label
    }

    // Prime the emission prefetch pipe (raw probabilities; log applied at use)
    float vb[PF], v0[PF], v1[PF];
#pragma unroll
    for (int k = 0; k < PF; ++k) {
        int t = min(1 + k, Tb - 1);
        vb[k] = base_b[(size_t)t * Vc];
        v0[k] = base_0[(size_t)t * Vc];
        v1[k] = base_1[(size_t)t * Vc];
    }

    // Per-step DP update (ln domain). Emission prob folded into the lane log:
    // m + log(sum * p) == m + log(sum) + log(p).
#define STEP(T_, K_) do {                                                     \
        float pbk = vb[K_] + EPSF;                                            \
        float p0k = v0[K_] + EPSF;                                            \
        float p1k = v1[K_] + EPSF;                                            \
        int tn = min((T_) + PF, Tb - 1);                                      \
        vb[K_] = base_b[(size_t)tn * Vc];                                     \
        v0[K_] = base_0[(size_t)tn * Vc];                                     \
        v1[K_] = base_1[(size_t)tn * Vc];                                     \
        float p3s = __shfl_up(a3, 1);                                         \
        float p2s = __shfl_up(a2, 1);                                         \
        if (l == 0) { p3s = NEGV; p2s = NEGV; }                               \
        /* j=0 (blank): logadd2(a0, p3s) + log(pb) */                         \
        float m0 = fmaxf(a0, p3s), w0 = fminf(a0, p3s);                       \
        float n0 = m0 + __logf((1.0f + __expf(w0 - m0)) * pbk);               \
        /* j=1 (label): logadd3(a1, a0, skip?p2s) + log(p0) */                \
        float c1 = allow1 ? p2s : NEGV;                                       \
        float m1 = fmaxf(fmaxf(a1, a0), c1);                                  \
        float n1 = m1 + __logf((__expf(a1 - m1) + __expf(a0 - m1)             \
                                + __expf(c1 - m1)) * p0k);                    \
        /* j=2 (blank): logadd2(a2, a1) + log(pb) */                          \
        float m2 = fmaxf(a2, a1), w2 = fminf(a2, a1);                         \
        float n2 = m2 + __logf((1.0f + __expf(w2 - m2)) * pbk);               \
        /* j=3 (label): logadd3(a3, a2, skip?a1) + log(p1) */                 \
        float c3 = allow3 ? a1 : NEGV;                                        \
        float m3 = fmaxf(fmaxf(a3, a2), c3);                                  \
        float n3 = m3 + __logf((__expf(a3 - m3) + __expf(a2 - m3)             \
                                + __expf(c3 - m3)) * p1k);                    \
        a0 = valid0 ? n0 : NEGV;                                              \
        a1 = valid1 ? n1 : NEGV;                                              \
        a2 = valid2 ? n2 : NEGV;                                              \
        a3 = valid3 ? n3 : NEGV;                                              \
    } while (0)

    int t = 1;
    while (t + PF <= Tb) {              // full tiles; slot k holds time t+k
#pragma unroll
        for (int k = 0; k < PF; ++k) {
            STEP(t + k, k);
        }
        t += PF;
    }
#pragma unroll
    for (int k = 0; k < PF; ++k) {      // tail: t ≡ 1 (mod PF) at entry
        if (t < Tb) { STEP(t, k); }
        ++t;
    }
#undef STEP

    // Final readout: loss = -ln( exp(a[2ll-1]) + exp(a[2ll]) )
    __shared__ float sh[256];
    sh[4 * l + 0] = a0; sh[4 * l + 1] = a1;
    sh[4 * l + 2] = a2; sh[4 * l + 3] = a3;
    __syncthreads();
    if (l == 0) {
        float x = sh[2 * ll - 1], y = sh[2 * ll];
        float m = fmaxf(x, y), w = fminf(x, y);
        loss[b] = -(m + __logf(1.0f + __expf(w - m)));
    }
}

__global__ void ctc_reduce_kernel(const float* __restrict__ loss,
                                  float* __restrict__ out, int B)
{
    int lane = threadIdx.x;             // one wave
    float x = (lane < B) ? loss[lane] : 0.0f;
#pragma unroll
    for (int off = 32; off > 0; off >>= 1)
        x += __shfl_down(x, off);
    if (lane == 0) out[0] = x / (float)B;
}

extern "C" void kernel_launch(void* const* d_in, const int* in_sizes, int n_in,
                              void* d_out, int out_size, void* d_ws, size_t ws_size,
                              hipStream_t stream)
{
    const float* pred   = (const float*)d_in[0];   // [B,T,V]
    const int*   ilen   = (const int*)d_in[1];     // [B,1]
    const int*   labels = (const int*)d_in[2];     // [B,L]
    const int*   llen   = (const int*)d_in[3];     // [B,1]
    float*       out    = (float*)d_out;
    float*       wsloss = (float*)d_ws;            // [B] scratch

    const int B = in_sizes[1];

    ctc_dp_kernel<<<B, 64, 0, stream>>>(pred, ilen, labels, llen, wsloss);
    ctc_reduce_kernel<<<1, 64, 0, stream>>>(wsloss, out, B);
}

// Round 4
// 426.752 us; speedup vs baseline: 1.9115x; 1.1101x over previous
//
#include <hip/hip_runtime.h>

#define NEGV  (-1e9f)
#define EPSF  (1e-7f)

constexpr int Tc = 1000;
constexpr int Vc = 1024;
constexpr int Lc = 100;
constexpr int GW = 128;          // gathered-emission row stride (floats)
constexpr int PF = 8;            // emission prefetch depth

// DPP wave_shr:1 == __shfl_up(x,1) but as a 2-cycle VALU op (no LDS path).
// Lane 0 receives `old` (we pass NEGV), folding the boundary fixup in.
#define SHFLUP1(x) __int_as_float(__builtin_amdgcn_update_dpp(            \
        __float_as_int(NEGV), __float_as_int(x), 0x138, 0xF, 0xF, false))

// Phase 1: E[b*Tc+t][j] = log(pred[b][t][col_j] + eps)
//   j in [0,100): label column labels[b][j];  j == 100: blank (Vc-1);
//   j in (100,128): 0 (padding so the DP kernel's dwordx2 reads are defined).
// One block per (b,t) row; the scatter happens here with 4.1M threads of
// parallelism instead of on the serial DP critical path.
__global__ __launch_bounds__(128) void ctc_gather_kernel(
    const float* __restrict__ pred,
    const int*   __restrict__ labels,
    float*       __restrict__ E)
{
    const int row = blockIdx.x;          // b*Tc + t
    const int j   = threadIdx.x;         // 0..127
    const int b   = row / Tc;
    float v = 0.0f;
    if (j <= 100) {
        const int col = (j < 100) ? labels[b * Lc + j] : (Vc - 1);
        v = __logf(pred[(size_t)row * Vc + col] + EPSF);
    }
    E[(size_t)row * GW + j] = v;
}

// Phase 2: one block = one wave = one batch element. Lane l owns extended
// lanes s = 4l..4l+3 in registers. Per step: 1 coalesced dwordx2 (labels) +
// 1 wave-uniform load (blank). No __syncthreads in the T loop.
template<bool USE_E>
__global__ __launch_bounds__(64) void ctc_dp_kernel(
    const float* __restrict__ pred,     // [B,T,V] probabilities
    const float* __restrict__ E,        // [B,T,GW] log-emissions (USE_E)
    const int*   __restrict__ ilen,     // [B,1]
    const int*   __restrict__ labels,   // [B,L]
    const int*   __restrict__ llen,     // [B,1]
    float*       __restrict__ loss)     // [B]
{
    const int b = blockIdx.x;
    const int l = threadIdx.x;          // 0..63

    const int il = ilen[b];
    const int ll = llen[b];
    const int Tb = min(Tc, il);         // reference freezes alpha at t >= il

    const int* lab = labels + b * Lc;
    const int lab0 = lab[min(2 * l,     Lc - 1)];
    const int lab1 = lab[min(2 * l + 1, Lc - 1)];
    const int labm = lab[max(2 * l - 1, 0)];
    const bool allow1 = (l == 0) || (lab0 != labm);
    const bool allow3 = (lab1 != lab0);

    const int Sv = 2 * ll + 1;
    const bool valid0 = (4 * l + 0) < Sv;
    const bool valid1 = (4 * l + 1) < Sv;
    const bool valid2 = (4 * l + 2) < Sv;
    const bool valid3 = (4 * l + 3) < Sv;

    const float* pb     = pred + (size_t)b * Tc * Vc;
    const float* base_b = pb + (Vc - 1);
    const float* base_0 = pb + lab0;
    const float* base_1 = pb + lab1;
    const float* Eb     = E + (size_t)b * Tc * GW;

    float a0 = NEGV, a1 = NEGV, a2 = NEGV, a3 = NEGV;
    if constexpr (USE_E) {
        if (l == 0) { a0 = Eb[100]; a1 = Eb[0]; }
    } else {
        if (l == 0) { a0 = __logf(base_b[0] + EPSF); a1 = __logf(base_0[0] + EPSF); }
    }

    float  vb[PF];
    float2 v01[PF];
    float  v0[PF], v1[PF];              // fallback path only (DCE'd otherwise)
#pragma unroll
    for (int k = 0; k < PF; ++k) {
        int t = min(1 + k, Tb - 1);
        if constexpr (USE_E) {
            vb[k]  = Eb[(size_t)t * GW + 100];
            v01[k] = *(const float2*)(Eb + (size_t)t * GW + 2 * l);
        } else {
            vb[k] = base_b[(size_t)t * Vc];
            v0[k] = base_0[(size_t)t * Vc];
            v1[k] = base_1[(size_t)t * Vc];
        }
    }

#define STEP(T_, K_) do {                                                     \
        float eb_, e0_, e1_;                                                  \
        if constexpr (USE_E) {                                                \
            eb_ = vb[K_]; e0_ = v01[K_].x; e1_ = v01[K_].y;                   \
        } else {                                                              \
            eb_ = __logf(vb[K_] + EPSF);                                      \
            e0_ = __logf(v0[K_] + EPSF);                                      \
            e1_ = __logf(v1[K_] + EPSF);                                      \
        }                                                                     \
        int tn = min((T_) + PF, Tb - 1);                                      \
        if constexpr (USE_E) {                                                \
            vb[K_]  = Eb[(size_t)tn * GW + 100];                              \
            v01[K_] = *(const float2*)(Eb + (size_t)tn * GW + 2 * l);         \
        } else {                                                              \
            vb[K_] = base_b[(size_t)tn * Vc];                                 \
            v0[K_] = base_0[(size_t)tn * Vc];                                 \
            v1[K_] = base_1[(size_t)tn * Vc];                                 \
        }                                                                     \
        float p3s = SHFLUP1(a3);                                              \
        float p2s = SHFLUP1(a2);                                              \
        /* shuffle-independent lanes first (overlap any xfer latency) */      \
        float m2 = fmaxf(a2, a1), w2 = fminf(a2, a1);                         \
        float n2 = m2 + __logf(1.0f + __expf(w2 - m2)) + eb_;                 \
        float c3 = allow3 ? a1 : NEGV;                                        \
        float m3 = fmaxf(fmaxf(a3, a2), c3);                                  \
        float n3 = m3 + __logf(__expf(a3 - m3) + __expf(a2 - m3)              \
                               + __expf(c3 - m3)) + e1_;                      \
        float m0 = fmaxf(a0, p3s), w0 = fminf(a0, p3s);                       \
        float n0 = m0 + __logf(1.0f + __expf(w0 - m0)) + eb_;                 \
        float c1 = allow1 ? p2s : NEGV;                                       \
        float m1 = fmaxf(fmaxf(a1, a0), c1);                                  \
        float n1 = m1 + __logf(__expf(a1 - m1) + __expf(a0 - m1)              \
                               + __expf(c1 - m1)) + e0_;                      \
        a0 = valid0 ? n0 : NEGV;                                              \
        a1 = valid1 ? n1 : NEGV;                                              \
        a2 = valid2 ? n2 : NEGV;                                              \
        a3 = valid3 ? n3 : NEGV;                                              \
    } while (0)

    int t = 1;
    while (t + PF <= Tb) {              // full tiles; slot k holds time t+k
#pragma unroll
        for (int k = 0; k < PF; ++k) {
            STEP(t + k, k);
        }
        t += PF;
    }
#pragma unroll
    for (int k = 0; k < PF; ++k) {      // tail: t ≡ 1 (mod PF) at entry
        if (t < Tb) { STEP(t, k); }
        ++t;
    }
#undef STEP

    // Readout: loss = -ln( exp(a[2ll-1]) + exp(a[2ll]) )
    __shared__ float sh[256];
    sh[4 * l + 0] = a0; sh[4 * l + 1] = a1;
    sh[4 * l + 2] = a2; sh[4 * l + 3] = a3;
    __syncthreads();
    if (l == 0) {
        float x = sh[2 * ll - 1], y = sh[2 * ll];
        float m = fmaxf(x, y), w = fminf(x, y);
        loss[b] = -(m + __logf(1.0f + __expf(w - m)));
    }
}

__global__ void ctc_reduce_kernel(const float* __restrict__ loss,
                                  float* __restrict__ out, int B)
{
    int lane = threadIdx.x;             // one wave
    float x = (lane < B) ? loss[lane] : 0.0f;
#pragma unroll
    for (int off = 32; off > 0; off >>= 1)
        x += __shfl_down(x, off);
    if (lane == 0) out[0] = x / (float)B;
}

extern "C" void kernel_launch(void* const* d_in, const int* in_sizes, int n_in,
                              void* d_out, int out_size, void* d_ws, size_t ws_size,
                              hipStream_t stream)
{
    const float* pred   = (const float*)d_in[0];   // [B,T,V]
    const int*   ilen   = (const int*)d_in[1];     // [B,1]
    const int*   labels = (const int*)d_in[2];     // [B,L]
    const int*   llen   = (const int*)d_in[3];     // [B,1]
    float*       out    = (float*)d_out;
    float*       wsloss = (float*)d_ws;            // [B] at ws offset 0

    const int B = in_sizes[1];

    const size_t lossBytes = 256;                  // B floats, padded
    const size_t Ebytes    = (size_t)B * Tc * GW * sizeof(float);

    if (ws_size >= lossBytes + Ebytes) {
        float* Ebuf = (float*)((char*)d_ws + lossBytes);
        ctc_gather_kernel<<<B * Tc, 128, 0, stream>>>(pred, labels, Ebuf);
        ctc_dp_kernel<true><<<B, 64, 0, stream>>>(pred, Ebuf, ilen, labels, llen, wsloss);
    } else {
        ctc_dp_kernel<false><<<B, 64, 0, stream>>>(pred, nullptr, ilen, labels, llen, wsloss);
    }
    ctc_reduce_kernel<<<1, 64, 0, stream>>>(wsloss, out, B);
}

// Round 5
// 270.340 us; speedup vs baseline: 3.0175x; 1.5786x over previous
//
#include <hip/hip_runtime.h>

#define EPSF  (1e-7f)
#define LN2F  (0.69314718055994530942f)

constexpr int Tc = 1000;
constexpr int Vc = 1024;
constexpr int Lc = 100;
constexpr int GW = 128;   // E row stride: slots [0..49]=labels 0,2,..98; 50=blank; [64..113]=labels 1,3,..99
constexpr int CH = 32;    // rows per LDS-staged chunk

// lane l-1 -> lane l (DPP wave_shr:1, 2-cycle VALU); lane 0 receives old = 0.
#define SHFLUP1Z(x) __int_as_float(__builtin_amdgcn_update_dpp( \
        0, __float_as_int(x), 0x138, 0xF, 0xF, false))

// one step of a wave-wide max butterfly (bound_ctrl=1 -> OOB reads give 0,
// identity for max of non-negative alphas)
#define DPPMAXSTEP(x, ctrl) \
    x = fmaxf(x, __int_as_float(__builtin_amdgcn_update_dpp( \
        0, __float_as_int(x), ctrl, 0xF, 0xF, true)))

// Phase 1: E[row][slot] = pred[row][col(slot)] + eps (LINEAR, no log).
// Slot layout groups even/odd labels so the DP kernel's per-lane LDS reads
// are stride-4B (conflict-free b32). Rows t >= input_length are skipped
// (never consumed by the DP; DMA may read their poison harmlessly).
__global__ __launch_bounds__(128) void ctc_gather_kernel(
    const float* __restrict__ pred,
    const int*   __restrict__ labels,
    const int*   __restrict__ ilen,
    float*       __restrict__ E)
{
    const int row = blockIdx.x;      // b*Tc + t
    const int j   = threadIdx.x;     // slot 0..127
    const int b   = row / Tc;
    const int t   = row - b * Tc;
    if (t >= ilen[b]) return;        // frozen rows never consumed
    const int* lab = labels + b * Lc;
    int col = -1;
    if (j < 64) {
        if (j < 50)       col = lab[2 * j];
        else if (j == 50) col = Vc - 1;          // blank
    } else {
        int k = j - 64;
        if (k < 50)       col = lab[2 * k + 1];
    }
    float v = 0.0f;
    if (col >= 0) v = pred[(size_t)row * Vc + col] + EPSF;
    E[(size_t)row * GW + j] = v;
}

// Phase 2: one block = one wave = one batch element. Lane l owns extended
// lanes s = 4l..4l+3 in registers, LINEAR domain with power-of-2 rescale
// every 8 steps. E rows staged through a 2x32-row LDS double buffer:
// 16 float4 loads issued at chunk start (pinned by sched_barrier), ds_writes
// after the chunk's compute (T14 async-split) -> HBM/L3 latency hidden.
__global__ __launch_bounds__(64) void ctc_dp_kernel(
    const float* __restrict__ E,        // [B,Tc,GW] linear p+eps
    const int*   __restrict__ ilen,     // [B,1]
    const int*   __restrict__ labels,   // [B,L]
    const int*   __restrict__ llen,     // [B,1]
    float*       __restrict__ loss)     // [B]
{
    const int b = blockIdx.x;
    const int l = threadIdx.x;          // 0..63

    const int il = ilen[b];
    const int ll = llen[b];
    const int Tb = min(Tc, il);         // steps t = 1..Tb-1 (>= 500 by data)

    const int* lab = labels + b * Lc;
    const int lab0 = lab[min(2 * l,     Lc - 1)];
    const int lab1 = lab[min(2 * l + 1, Lc - 1)];
    const int labm = lab[max(2 * l - 1, 0)];
    const bool allow1 = (l == 0) || (lab0 != labm);
    const bool allow3 = (lab1 != lab0);

    const int Sv = 2 * ll + 1;
    const bool valid0 = (4 * l + 0) < Sv;
    const bool valid1 = (4 * l + 1) < Sv;
    const bool valid2 = (4 * l + 2) < Sv;
    const bool valid3 = (4 * l + 3) < Sv;

    const float* Eb = E + (size_t)b * Tc * GW;

    __shared__ float lds[2][CH][GW];    // 32 KiB double buffer
    __shared__ float sh[256];

    // t = 0 init (linear): s=0 blank, s=1 first label
    float a0 = 0.0f, a1 = 0.0f, a2 = 0.0f, a3 = 0.0f;
    if (l == 0) { a0 = Eb[50]; a1 = Eb[0]; }
    int Eshift = 0;                      // true alpha = stored * 2^Eshift

#define STEP(Lb, r) do {                                                      \
        float e0_ = (Lb)[(r) * GW + l];                                       \
        float e1_ = (Lb)[(r) * GW + 64 + l];                                  \
        float eb_ = (Lb)[(r) * GW + 50];                                      \
        float p3s_ = SHFLUP1Z(a3);                                            \
        float p2s_ = SHFLUP1Z(a2);                                            \
        float n0_ = (a0 + p3s_) * eb_;                                        \
        float c1_ = allow1 ? p2s_ : 0.0f;                                     \
        float n1_ = (a1 + a0 + c1_) * e0_;                                    \
        float n2_ = (a2 + a1) * eb_;                                          \
        float c3_ = allow3 ? a1 : 0.0f;                                       \
        float n3_ = (a3 + a2 + c3_) * e1_;                                    \
        a0 = valid0 ? n0_ : 0.0f;                                             \
        a1 = valid1 ? n1_ : 0.0f;                                             \
        a2 = valid2 ? n2_ : 0.0f;                                             \
        a3 = valid3 ? n3_ : 0.0f;                                             \
    } while (0)

#define RESCALE() do {                                                        \
        float m_ = fmaxf(fmaxf(a0, a1), fmaxf(a2, a3));                       \
        DPPMAXSTEP(m_, 0x111);  /* row_shr:1  */                              \
        DPPMAXSTEP(m_, 0x112);  /* row_shr:2  */                              \
        DPPMAXSTEP(m_, 0x114);  /* row_shr:4  */                              \
        DPPMAXSTEP(m_, 0x118);  /* row_shr:8  */                              \
        DPPMAXSTEP(m_, 0x142);  /* row_bcast:15 */                            \
        DPPMAXSTEP(m_, 0x143);  /* row_bcast:31 */                            \
        int mb_ = __builtin_amdgcn_readlane(__float_as_int(m_), 63);          \
        int Ee_ = (mb_ >> 23) & 0xFF;                                         \
        float sc_ = __int_as_float((253 - Ee_) << 23);  /* 2^(126-Ee) */      \
        a0 *= sc_; a1 *= sc_; a2 *= sc_; a3 *= sc_;                           \
        Eshift += Ee_ - 126;                                                  \
    } while (0)

    // Pair p covers rows (t0n+2p, t0n+2p+1); t0n is 32-aligned (or 0) so any
    // consumed row (< Tb <= Tc) sits in an unclamped exact pair; clamped
    // pairs (rows >= Tc) are never consumed.
#define LOADCHUNK(t0n_) do {                                                  \
        _Pragma("unroll")                                                     \
        for (int p_ = 0; p_ < 16; ++p_) {                                     \
            int r0_ = min((t0n_) + 2 * p_, Tc - 2);                           \
            g[p_] = *(const float4*)(Eb + (size_t)r0_ * GW + 4 * l);          \
        }                                                                     \
    } while (0)

#define WRITECHUNK(buf_) do {                                                 \
        float* d_ = &lds[buf_][0][0] + 4 * l;                                 \
        _Pragma("unroll")                                                     \
        for (int p_ = 0; p_ < 16; ++p_) {                                     \
            *(float4*)(d_ + p_ * 2 * GW) = g[p_];                             \
        }                                                                     \
    } while (0)

    float4 g[16];

    // prologue: stage rows 0..31 into buf 0 (the one exposed-latency stall)
    LOADCHUNK(0);
    __builtin_amdgcn_sched_barrier(0);
    WRITECHUNK(0);
    int buf = 0;

    // chunk 0: steps r = 1..31 (Tb >= 500 so this chunk is always full)
    {
        const bool pf = (CH < Tb);
        if (pf) LOADCHUNK(CH);
        __builtin_amdgcn_sched_barrier(0);
        const float* Lb = &lds[0][0][0];
#pragma unroll
        for (int k = 1; k < 8; ++k) STEP(Lb, k);
        RESCALE();
#pragma unroll
        for (int gi = 1; gi < 4; ++gi) {
#pragma unroll
            for (int k = 0; k < 8; ++k) STEP(Lb, gi * 8 + k);
            RESCALE();
        }
        if (pf) WRITECHUNK(1);
        buf = 1;
    }

    for (int t0 = CH; t0 < Tb; t0 += CH) {
        const int t0n = t0 + CH;
        const bool pf = (t0n < Tb);
        if (pf) LOADCHUNK(t0n);
        __builtin_amdgcn_sched_barrier(0);
        const float* Lb = &lds[buf][0][0];
        const int ns = min(CH, Tb - t0);
        if (ns == CH) {
#pragma unroll
            for (int gi = 0; gi < 4; ++gi) {
#pragma unroll
                for (int k = 0; k < 8; ++k) STEP(Lb, gi * 8 + k);
                RESCALE();
            }
        } else {
            for (int r = 0; r < ns; ++r) {
                STEP(Lb, r);
                if ((r & 7) == 7) RESCALE();
            }
        }
        if (pf) WRITECHUNK(buf ^ 1);
        buf ^= 1;
    }
#undef STEP
#undef RESCALE
#undef LOADCHUNK
#undef WRITECHUNK

    // Readout: loglik = ln(a[2ll-1] + a[2ll]) + Eshift*ln2
    sh[4 * l + 0] = a0; sh[4 * l + 1] = a1;
    sh[4 * l + 2] = a2; sh[4 * l + 3] = a3;
    __syncthreads();
    if (l == 0) {
        float x = sh[2 * ll - 1], y = sh[2 * ll];
        loss[b] = -(__logf(x + y) + (float)Eshift * LN2F);
    }
}

__global__ void ctc_reduce_kernel(const float* __restrict__ loss,
                                  float* __restrict__ out, int B)
{
    int lane = threadIdx.x;             // one wave
    float x = (lane < B) ? loss[lane] : 0.0f;
#pragma unroll
    for (int off = 32; off > 0; off >>= 1)
        x += __shfl_down(x, off);
    if (lane == 0) out[0] = x / (float)B;
}

extern "C" void kernel_launch(void* const* d_in, const int* in_sizes, int n_in,
                              void* d_out, int out_size, void* d_ws, size_t ws_size,
                              hipStream_t stream)
{
    const float* pred   = (const float*)d_in[0];   // [B,T,V]
    const int*   ilen   = (const int*)d_in[1];     // [B,1]
    const int*   labels = (const int*)d_in[2];     // [B,L]
    const int*   llen   = (const int*)d_in[3];     // [B,1]
    float*       out    = (float*)d_out;
    float*       wsloss = (float*)d_ws;            // [B] at ws offset 0
    float*       Ebuf   = (float*)((char*)d_ws + 256);

    const int B = in_sizes[1];

    ctc_gather_kernel<<<B * Tc, 128, 0, stream>>>(pred, labels, ilen, Ebuf);
    ctc_dp_kernel<<<B, 64, 0, stream>>>(Ebuf, ilen, labels, llen, wsloss);
    ctc_reduce_kernel<<<1, 64, 0, stream>>>(wsloss, out, B);
}

// Round 6
// 260.429 us; speedup vs baseline: 3.1323x; 1.0381x over previous
//
#include <hip/hip_runtime.h>

#define EPSF  (1e-7f)
#define LN2F  (0.69314718055994530942f)

constexpr int Tc = 1000;
constexpr int Vc = 1024;
constexpr int Lc = 100;
constexpr int GW = 128;   // E row: [0..49]=labels 0,2,..98; 50=blank; [64..113]=labels 1,3,..99; rest 0

// lane l-1 -> lane l (DPP wave_shr:1, 2-cycle VALU); lane 0 receives old = 0.
#define SHFLUP1Z(x) __int_as_float(__builtin_amdgcn_update_dpp( \
        0, __float_as_int(x), 0x138, 0xF, 0xF, false))

// wave-max butterfly step (bound_ctrl=1 -> OOB lanes give 0, identity for max
// of non-negative alphas)
#define DPPMAXSTEP(x, ctrl) \
    x = fmaxf(x, __int_as_float(__builtin_amdgcn_update_dpp( \
        0, __float_as_int(x), ctrl, 0xF, 0xF, true)))

// Phase 1: E[row][slot] = pred[row][col(slot)] + eps (linear domain).
// Slots whose label index >= label_length are written 0 -> invalid DP lanes
// stay exactly 0 in the DP kernel with no per-step masking (zero-propagation:
// an invalid blank lane's sources are themselves invalid by parity).
__global__ __launch_bounds__(128) void ctc_gather_kernel(
    const float* __restrict__ pred,
    const int*   __restrict__ labels,
    const int*   __restrict__ ilen,
    const int*   __restrict__ llen,
    float*       __restrict__ E)
{
    const int row = blockIdx.x;      // b*Tc + t
    const int j   = threadIdx.x;     // slot 0..127
    const int b   = row / Tc;
    const int t   = row - b * Tc;
    if (t >= ilen[b]) return;        // frozen rows are never consumed
    const int ll = llen[b];
    const int* lab = labels + b * Lc;
    float v = 0.0f;
    if (j < 64) {
        if (j < 50) {
            if (2 * j < ll) v = pred[(size_t)row * Vc + lab[2 * j]] + EPSF;
        } else if (j == 50) {
            v = pred[(size_t)row * Vc + (Vc - 1)] + EPSF;   // blank
        }
    } else {
        int k = j - 64;
        if (k < 50 && (2 * k + 1) < ll)
            v = pred[(size_t)row * Vc + lab[2 * k + 1]] + EPSF;
    }
    E[(size_t)row * GW + j] = v;
}

// Phase 2: one block = one wave = one batch element. Lane l owns extended
// lanes s = 4l..4l+3 in registers, LINEAR domain, power-of-2 rescale every 8
// steps. Emissions flow through a 32-row REGISTER pipe loaded directly from
// E (lane l's columns are fixed: l, 64+l, 50) -- no LDS round trip, counted
// vmcnt, 24-step lookahead. sched_barrier(0) per 8-step group pins the
// schedule so the compiler can't sink the prefetch (R4 failure mode).
__global__ __launch_bounds__(64) void ctc_dp_kernel(
    const float* __restrict__ E,        // [B,Tc,GW] linear p+eps (masked)
    const int*   __restrict__ ilen,     // [B,1]
    const int*   __restrict__ labels,   // [B,L]
    const int*   __restrict__ llen,     // [B,1]
    float*       __restrict__ loss)     // [B]
{
    const int b = blockIdx.x;
    const int l = threadIdx.x;          // 0..63

    const int il = ilen[b];
    const int ll = llen[b];
    const int Tb = min(Tc, il);         // steps t = 1..Tb-1 (Tb >= 500 by data)

    const int* lab = labels + b * Lc;
    const int lab0 = lab[min(2 * l,     Lc - 1)];
    const int lab1 = lab[min(2 * l + 1, Lc - 1)];
    const int labm = lab[max(2 * l - 1, 0)];
    const float allow1f = ((l == 0) || (lab0 != labm)) ? 1.0f : 0.0f;
    const float allow3f = (lab1 != lab0) ? 1.0f : 0.0f;

    const float* Eb = E + (size_t)b * Tc * GW;

    __shared__ float sh[256];

    // t = 0 init (linear): s=0 blank, s=1 first label
    float a0 = 0.0f, a1 = 0.0f, a2 = 0.0f, a3 = 0.0f;
    if (l == 0) { a0 = Eb[50]; a1 = Eb[0]; }
    int Eshift = 0;                     // true alpha = stored * 2^Eshift

    float v0[32], v1[32], vb[32];       // register pipe, static indices only

#define LOADG(gi, baseRow) do {                                               \
        const int br_ = (baseRow);                                            \
        if (br_ + 7 <= Tc - 1) {                                              \
            const float* p_ = Eb + (size_t)br_ * GW;                          \
            _Pragma("unroll")                                                 \
            for (int k_ = 0; k_ < 8; ++k_) {                                  \
                v0[8 * (gi) + k_] = p_[k_ * GW + l];                          \
                v1[8 * (gi) + k_] = p_[k_ * GW + 64 + l];                     \
                vb[8 * (gi) + k_] = p_[k_ * GW + 50];                         \
            }                                                                 \
        } else {                                                              \
            _Pragma("unroll")                                                 \
            for (int k_ = 0; k_ < 8; ++k_) {                                  \
                int r_ = min(br_ + k_, Tc - 1);  /* in-slice, maybe stale */  \
                const float* p_ = Eb + (size_t)r_ * GW;                       \
                v0[8 * (gi) + k_] = p_[l];                                    \
                v1[8 * (gi) + k_] = p_[64 + l];                               \
                vb[8 * (gi) + k_] = p_[50];                                   \
            }                                                                 \
        }                                                                     \
    } while (0)

#define STEP(gi, k) do {                                                      \
        float e0_ = v0[8 * (gi) + (k)];                                       \
        float e1_ = v1[8 * (gi) + (k)];                                       \
        float eb_ = vb[8 * (gi) + (k)];                                       \
        float p3s_ = SHFLUP1Z(a3);                                            \
        float p2s_ = SHFLUP1Z(a2);                                            \
        float n0_ = (a0 + p3s_) * eb_;                                        \
        float n1_ = fmaf(p2s_, allow1f, a1 + a0) * e0_;                       \
        float n2_ = (a2 + a1) * eb_;                                          \
        float n3_ = fmaf(a1, allow3f, a3 + a2) * e1_;                         \
        a0 = n0_; a1 = n1_; a2 = n2_; a3 = n3_;                               \
    } while (0)

#define RESCALE() do {                                                        \
        float m_ = fmaxf(fmaxf(a0, a1), fmaxf(a2, a3));                       \
        DPPMAXSTEP(m_, 0x111);  /* row_shr:1  */                              \
        DPPMAXSTEP(m_, 0x112);  /* row_shr:2  */                              \
        DPPMAXSTEP(m_, 0x114);  /* row_shr:4  */                              \
        DPPMAXSTEP(m_, 0x118);  /* row_shr:8  */                              \
        DPPMAXSTEP(m_, 0x142);  /* row_bcast:15 */                            \
        DPPMAXSTEP(m_, 0x143);  /* row_bcast:31 */                            \
        int mb_ = __builtin_amdgcn_readlane(__float_as_int(m_), 63);          \
        int Ee_ = (mb_ >> 23) & 0xFF;                                         \
        float sc_ = __int_as_float((253 - Ee_) << 23);  /* 2^(126-Ee) */      \
        a0 *= sc_; a1 *= sc_; a2 *= sc_; a3 *= sc_;                           \
        Eshift += Ee_ - 126;                                                  \
    } while (0)

    // prologue: fill the 32-row pipe (rows 1..32); one exposed latency hit
    LOADG(0, 1); LOADG(1, 9); LOADG(2, 17); LOADG(3, 25);

    // invariant at loop head: slot (g,k) holds row t0 + 8g + k
    int t0 = 1;
    for (; t0 + 32 <= Tb; t0 += 32) {
        __builtin_amdgcn_sched_barrier(0);
#pragma unroll
        for (int k = 0; k < 8; ++k) STEP(0, k);
        RESCALE();
        LOADG(0, t0 + 32);
        __builtin_amdgcn_sched_barrier(0);
#pragma unroll
        for (int k = 0; k < 8; ++k) STEP(1, k);
        RESCALE();
        LOADG(1, t0 + 40);
        __builtin_amdgcn_sched_barrier(0);
#pragma unroll
        for (int k = 0; k < 8; ++k) STEP(2, k);
        RESCALE();
        LOADG(2, t0 + 48);
        __builtin_amdgcn_sched_barrier(0);
#pragma unroll
        for (int k = 0; k < 8; ++k) STEP(3, k);
        RESCALE();
        LOADG(3, t0 + 56);
    }

    // tail: up to 31 remaining steps, uniform guards, no refills
#pragma unroll
    for (int g = 0; g < 4; ++g) {
        __builtin_amdgcn_sched_barrier(0);
#pragma unroll
        for (int k = 0; k < 8; ++k) {
            if (t0 + 8 * g + k < Tb) STEP(g, k);
        }
        RESCALE();
    }
#undef LOADG
#undef STEP
#undef RESCALE

    // Readout: loglik = ln(a[2ll-1] + a[2ll]) + Eshift*ln2
    sh[4 * l + 0] = a0; sh[4 * l + 1] = a1;
    sh[4 * l + 2] = a2; sh[4 * l + 3] = a3;
    __syncthreads();
    if (l == 0) {
        float x = sh[2 * ll - 1], y = sh[2 * ll];
        loss[b] = -(__logf(x + y) + (float)Eshift * LN2F);
    }
}

__global__ void ctc_reduce_kernel(const float* __restrict__ loss,
                                  float* __restrict__ out, int B)
{
    int lane = threadIdx.x;             // one wave
    float x = (lane < B) ? loss[lane] : 0.0f;
#pragma unroll
    for (int off = 32; off > 0; off >>= 1)
        x += __shfl_down(x, off);
    if (lane == 0) out[0] = x / (float)B;
}

extern "C" void kernel_launch(void* const* d_in, const int* in_sizes, int n_in,
                              void* d_out, int out_size, void* d_ws, size_t ws_size,
                              hipStream_t stream)
{
    const float* pred   = (const float*)d_in[0];   // [B,T,V]
    const int*   ilen   = (const int*)d_in[1];     // [B,1]
    const int*   labels = (const int*)d_in[2];     // [B,L]
    const int*   llen   = (const int*)d_in[3];     // [B,1]
    float*       out    = (float*)d_out;
    float*       wsloss = (float*)d_ws;            // [B] at ws offset 0
    float*       Ebuf   = (float*)((char*)d_ws + 256);

    const int B = in_sizes[1];

    ctc_gather_kernel<<<B * Tc, 128, 0, stream>>>(pred, labels, ilen, llen, Ebuf);
    ctc_dp_kernel<<<B, 64, 0, stream>>>(Ebuf, ilen, labels, llen, wsloss);
    ctc_reduce_kernel<<<1, 64, 0, stream>>>(wsloss, out, B);
}